// Round 1
// baseline (735.012 us; speedup 1.0000x reference)
//
#include <hip/hip_runtime.h>

#define NH    12
#define HD    64
#define HDIM  768
#define BATCH 2
#define SEQ   2048
#define MTOT  (BATCH*SEQ)   // 4096

// ---------------------------------------------------------------------------
// GEMM: Y = X @ W^T + bias.   X: M x K row-major.   W: N x K row-major
// (einsum 'bsh,oh->bso' => B[k][n] = W[n*K+k], i.e. W rows contiguous in K).
// 128x128 tile, 256 threads, 8x8 per thread, K-step 16, single-buffered LDS.
// MODE 0: plain store Y[m*Ndim + n]
// MODE 1: scatter to Q/K/V layout [((b*NH+h)*SEQ + s)*HD + d]
// ---------------------------------------------------------------------------
template<int MODE>
__device__ __forceinline__ void gemm_body(
    const float* __restrict__ X, const float* __restrict__ W,
    const float* __restrict__ bias, float* __restrict__ Y,
    int Kdim, int Ndim, int m0, int n0)
{
    __shared__ float As[16][128];   // As[k][m]
    __shared__ float Bs[16][128];   // Bs[k][n]

    const int tid = threadIdx.x;
    const int tx  = tid & 15;         // n sub-block 0..15
    const int ty  = tid >> 4;         // m sub-block 0..15
    const int lm  = tid & 127;        // load row (m or n)
    const int lk  = (tid >> 7) << 3;  // 0 or 8

    const float* __restrict__ xrow = X + (size_t)(m0 + lm) * Kdim + lk;
    const float* __restrict__ wrow = W + (size_t)(n0 + lm) * Kdim + lk;

    float acc[8][8];
    #pragma unroll
    for (int i = 0; i < 8; ++i)
        #pragma unroll
        for (int j = 0; j < 8; ++j) acc[i][j] = 0.f;

    for (int k0 = 0; k0 < Kdim; k0 += 16) {
        const float4 xa = *(const float4*)(xrow + k0);
        const float4 xb = *(const float4*)(xrow + k0 + 4);
        const float4 wa = *(const float4*)(wrow + k0);
        const float4 wb = *(const float4*)(wrow + k0 + 4);
        __syncthreads();
        As[lk+0][lm]=xa.x; As[lk+1][lm]=xa.y; As[lk+2][lm]=xa.z; As[lk+3][lm]=xa.w;
        As[lk+4][lm]=xb.x; As[lk+5][lm]=xb.y; As[lk+6][lm]=xb.z; As[lk+7][lm]=xb.w;
        Bs[lk+0][lm]=wa.x; Bs[lk+1][lm]=wa.y; Bs[lk+2][lm]=wa.z; Bs[lk+3][lm]=wa.w;
        Bs[lk+4][lm]=wb.x; Bs[lk+5][lm]=wb.y; Bs[lk+6][lm]=wb.z; Bs[lk+7][lm]=wb.w;
        __syncthreads();
        #pragma unroll
        for (int kk = 0; kk < 16; ++kk) {
            const float4 a0 = *(const float4*)&As[kk][ty*8];
            const float4 a1 = *(const float4*)&As[kk][ty*8+4];
            const float4 b0 = *(const float4*)&Bs[kk][tx*8];
            const float4 b1 = *(const float4*)&Bs[kk][tx*8+4];
            const float a[8] = {a0.x,a0.y,a0.z,a0.w,a1.x,a1.y,a1.z,a1.w};
            const float b[8] = {b0.x,b0.y,b0.z,b0.w,b1.x,b1.y,b1.z,b1.w};
            #pragma unroll
            for (int i = 0; i < 8; ++i)
                #pragma unroll
                for (int j = 0; j < 8; ++j)
                    acc[i][j] = fmaf(a[i], b[j], acc[i][j]);
        }
    }

    #pragma unroll
    for (int i = 0; i < 8; ++i) {
        const int m = m0 + ty*8 + i;
        const int n = n0 + tx*8;
        if (MODE == 0) {
            float o[8];
            #pragma unroll
            for (int j = 0; j < 8; ++j) o[j] = acc[i][j] + bias[n+j];
            *(float4*)&Y[(size_t)m*Ndim + n]     = make_float4(o[0],o[1],o[2],o[3]);
            *(float4*)&Y[(size_t)m*Ndim + n + 4] = make_float4(o[4],o[5],o[6],o[7]);
        } else {
            const int bb = m >> 11, ss = m & (SEQ-1);
            #pragma unroll
            for (int j = 0; j < 8; ++j) {
                const int nn = n + j;
                const int hh = nn >> 6, dd = nn & (HD-1);
                Y[((size_t)(bb*NH + hh)*SEQ + ss)*HD + dd] = acc[i][j] + bias[nn];
            }
        }
    }
}

__global__ __launch_bounds__(256) void qkv_kernel(
    const float* __restrict__ X,
    const float* __restrict__ wq, const float* __restrict__ bq,
    const float* __restrict__ wk, const float* __restrict__ bk,
    const float* __restrict__ wv, const float* __restrict__ bv,
    float* __restrict__ qo, float* __restrict__ ko, float* __restrict__ vo)
{
    const int z = blockIdx.z;
    const float* W    = (z == 0) ? wq : (z == 1) ? wk : wv;
    const float* bias = (z == 0) ? bq : (z == 1) ? bk : bv;
    float*       Y    = (z == 0) ? qo : (z == 1) ? ko : vo;
    gemm_body<1>(X, W, bias, Y, HDIM, HDIM, blockIdx.x * 128, blockIdx.y * 128);
}

__global__ __launch_bounds__(256) void outproj_kernel(
    const float* __restrict__ X, const float* __restrict__ W,
    const float* __restrict__ bias, float* __restrict__ Y)
{
    gemm_body<0>(X, W, bias, Y, HDIM, HDIM, blockIdx.x * 128, blockIdx.y * 128);
}

// ---------------------------------------------------------------------------
// Flash attention, fp32. Block = 256 threads = one (b, h, 64-row q-tile).
// LDS: QT[d][i] (pre-scaled by 1/8), KT[d][j] (reused as PT[j][i]), Vs[j][d].
// Stride 68 spreads banks for the transposed fragment reads.
// Thread (ti,tj) owns S[4ti..+4][4tj..+4] and O[4ti..+4][4tj..+4].
// Row softmax reduces across the 16 tj lanes (same wave).
// ---------------------------------------------------------------------------
__global__ __launch_bounds__(256) void attn_kernel(
    const float* __restrict__ Q, const float* __restrict__ K,
    const float* __restrict__ V, const int* __restrict__ mask,
    float* __restrict__ ctx)
{
    __shared__ float QT[64][68];
    __shared__ float KT[64][68];   // K tile transposed; then reused as PT[j][i]
    __shared__ float Vs[64][68];

    const int tid = threadIdx.x;
    const int q0  = blockIdx.x * 64;
    const int h   = blockIdx.y;
    const int b   = blockIdx.z;
    const size_t hb = (size_t)(b*NH + h) * SEQ * HD;

    // ---- load Q tile, transposed + pre-scaled by 1/sqrt(HD) ----
    {
        const int r  = tid >> 2;          // 0..63
        const int c0 = (tid & 3) << 4;    // 0,16,32,48
        const float* src = Q + hb + (size_t)(q0 + r) * HD + c0;
        const float4 v0 = ((const float4*)src)[0];
        const float4 v1 = ((const float4*)src)[1];
        const float4 v2 = ((const float4*)src)[2];
        const float4 v3 = ((const float4*)src)[3];
        const float qa[16] = {v0.x,v0.y,v0.z,v0.w, v1.x,v1.y,v1.z,v1.w,
                              v2.x,v2.y,v2.z,v2.w, v3.x,v3.y,v3.z,v3.w};
        #pragma unroll
        for (int u = 0; u < 16; ++u) QT[c0+u][r] = qa[u] * 0.125f;
    }

    const int ti = tid >> 4;   // 0..15 (row group)
    const int tj = tid & 15;   // 0..15 (col group)

    float m_i[4], l_i[4], O[4][4];
    #pragma unroll
    for (int i = 0; i < 4; ++i) {
        m_i[i] = -1e30f; l_i[i] = 0.f;
        #pragma unroll
        for (int d = 0; d < 4; ++d) O[i][d] = 0.f;
    }

    for (int t = 0; t < SEQ/64; ++t) {
        __syncthreads();   // prior tile's PV done -> KT/Vs reusable (also covers Q load)
        {
            const int r  = tid >> 2;
            const int c0 = (tid & 3) << 4;
            const float* ks = K + hb + (size_t)(t*64 + r) * HD + c0;
            const float* vs = V + hb + (size_t)(t*64 + r) * HD + c0;
            const float4 k0 = ((const float4*)ks)[0];
            const float4 k1 = ((const float4*)ks)[1];
            const float4 k2 = ((const float4*)ks)[2];
            const float4 k3 = ((const float4*)ks)[3];
            const float ka[16] = {k0.x,k0.y,k0.z,k0.w, k1.x,k1.y,k1.z,k1.w,
                                  k2.x,k2.y,k2.z,k2.w, k3.x,k3.y,k3.z,k3.w};
            #pragma unroll
            for (int u = 0; u < 16; ++u) KT[c0+u][r] = ka[u];
            *(float4*)&Vs[r][c0+ 0] = ((const float4*)vs)[0];
            *(float4*)&Vs[r][c0+ 4] = ((const float4*)vs)[1];
            *(float4*)&Vs[r][c0+ 8] = ((const float4*)vs)[2];
            *(float4*)&Vs[r][c0+12] = ((const float4*)vs)[3];
        }
        __syncthreads();

        // ---- S = (Q/8) K^T ----
        float s[4][4];
        #pragma unroll
        for (int i = 0; i < 4; ++i)
            #pragma unroll
            for (int j = 0; j < 4; ++j) s[i][j] = 0.f;

        #pragma unroll 8
        for (int d = 0; d < 64; ++d) {
            const float4 qv = *(const float4*)&QT[d][ti*4];
            const float4 kv = *(const float4*)&KT[d][tj*4];
            const float qa[4] = {qv.x, qv.y, qv.z, qv.w};
            const float ka[4] = {kv.x, kv.y, kv.z, kv.w};
            #pragma unroll
            for (int i = 0; i < 4; ++i)
                #pragma unroll
                for (int j = 0; j < 4; ++j)
                    s[i][j] = fmaf(qa[i], ka[j], s[i][j]);
        }

        // ---- mask (all-ones in this problem, kept for fidelity) ----
        #pragma unroll
        for (int jj = 0; jj < 4; ++jj) {
            if (mask[b*SEQ + t*64 + tj*4 + jj] == 0) {
                #pragma unroll
                for (int ii = 0; ii < 4; ++ii) s[ii][jj] = -1e9f;
            }
        }

        // ---- online softmax (row reduce across 16 tj lanes) ----
        float p[4][4];
        #pragma unroll
        for (int ii = 0; ii < 4; ++ii) {
            float tmax = fmaxf(fmaxf(s[ii][0], s[ii][1]), fmaxf(s[ii][2], s[ii][3]));
            #pragma unroll
            for (int off = 1; off < 16; off <<= 1)
                tmax = fmaxf(tmax, __shfl_xor(tmax, off, 16));
            const float mnew = fmaxf(m_i[ii], tmax);
            const float sc   = __expf(m_i[ii] - mnew);
            float ps = 0.f;
            #pragma unroll
            for (int jj = 0; jj < 4; ++jj) {
                p[ii][jj] = __expf(s[ii][jj] - mnew);
                ps += p[ii][jj];
            }
            #pragma unroll
            for (int off = 1; off < 16; off <<= 1)
                ps += __shfl_xor(ps, off, 16);
            l_i[ii] = l_i[ii] * sc + ps;
            m_i[ii] = mnew;
            #pragma unroll
            for (int dd = 0; dd < 4; ++dd) O[ii][dd] *= sc;
        }

        __syncthreads();   // all waves done reading KT
        // ---- PT[j][i] = P[i][j], stored into KT's LDS ----
        #pragma unroll
        for (int jj = 0; jj < 4; ++jj)
            #pragma unroll
            for (int ii = 0; ii < 4; ++ii)
                KT[tj*4+jj][ti*4+ii] = p[ii][jj];
        __syncthreads();

        // ---- O += P V ----
        #pragma unroll 8
        for (int j = 0; j < 64; ++j) {
            const float4 pv = *(const float4*)&KT[j][ti*4];
            const float4 vv = *(const float4*)&Vs[j][tj*4];
            const float pa[4] = {pv.x, pv.y, pv.z, pv.w};
            const float va[4] = {vv.x, vv.y, vv.z, vv.w};
            #pragma unroll
            for (int ii = 0; ii < 4; ++ii)
                #pragma unroll
                for (int dd = 0; dd < 4; ++dd)
                    O[ii][dd] = fmaf(pa[ii], va[dd], O[ii][dd]);
        }
    }

    // ---- epilogue: normalize and store ctx[b][s][h*64+d] ----
    #pragma unroll
    for (int ii = 0; ii < 4; ++ii) {
        const float inv = 1.0f / l_i[ii];
        const int row = q0 + ti*4 + ii;
        const float4 o = make_float4(O[ii][0]*inv, O[ii][1]*inv,
                                     O[ii][2]*inv, O[ii][3]*inv);
        *(float4*)&ctx[((size_t)(b*SEQ + row))*HDIM + h*HD + tj*4] = o;
    }
}

extern "C" void kernel_launch(void* const* d_in, const int* in_sizes, int n_in,
                              void* d_out, int out_size, void* d_ws, size_t ws_size,
                              hipStream_t stream) {
    const float* hs   = (const float*)d_in[0];
    const int*   msk  = (const int*)  d_in[1];
    const float* wq   = (const float*)d_in[2];
    const float* bq   = (const float*)d_in[3];
    const float* wk   = (const float*)d_in[4];
    const float* bk   = (const float*)d_in[5];
    const float* wv   = (const float*)d_in[6];
    const float* bv   = (const float*)d_in[7];
    const float* wo   = (const float*)d_in[8];
    const float* bo   = (const float*)d_in[9];
    float* out = (float*)d_out;

    const size_t NQ = (size_t)BATCH * NH * SEQ * HD;  // 3,145,728 floats
    float* qw = (float*)d_ws;
    float* kw = qw + NQ;
    float* vw = kw + NQ;
    float* cw = vw + NQ;   // ctx [B][S][H]

    qkv_kernel<<<dim3(MTOT/128, HDIM/128, 3), 256, 0, stream>>>(
        hs, wq, bq, wk, bk, wv, bv, qw, kw, vw);
    attn_kernel<<<dim3(SEQ/64, NH, BATCH), 256, 0, stream>>>(
        qw, kw, vw, msk, cw);
    outproj_kernel<<<dim3(MTOT/128, HDIM/128), 256, 0, stream>>>(
        cw, wo, bo, out);
}

// Round 2
// 242.004 us; speedup vs baseline: 3.0372x; 3.0372x over previous
//
#include <hip/hip_runtime.h>

#define NH   12
#define HD   64
#define H    768
#define B_   2
#define S_   2048
#define MTOT (B_*S_)   // 4096
#define KS   1536      // split storage width: [hi(768) | lo(768)]
#define KP   2304      // GEMM k' extent: hi*hi | hi*lo | lo*hi

typedef short bf16x8 __attribute__((ext_vector_type(8)));
typedef float f32x4  __attribute__((ext_vector_type(4)));

#define MFMA(a,b,c) __builtin_amdgcn_mfma_f32_16x16x32_bf16((a),(b),(c),0,0,0)
#define GLL16(g,l) __builtin_amdgcn_global_load_lds( \
    (const __attribute__((address_space(1))) void*)(g), \
    (__attribute__((address_space(3))) void*)(l), 16, 0, 0)

__device__ __forceinline__ unsigned short f2bf(float x){
    union { float f; unsigned u; } c; c.f = x;
    unsigned r = (c.u + 0x7FFFu + ((c.u >> 16) & 1u)) >> 16;   // RNE
    return (unsigned short)r;
}
__device__ __forceinline__ float bf2f(unsigned short b){
    union { unsigned u; float f; } c; c.u = ((unsigned)b) << 16;
    return c.f;
}

// ---------------------------------------------------------------------------
// Split pre-passes: fp32 row [768] -> bf16 [hi(768) | lo(768)]
// ---------------------------------------------------------------------------
__global__ __launch_bounds__(256) void split_x(
    const float* __restrict__ src, unsigned short* __restrict__ dst)
{
    const int m = blockIdx.x;
    const float* s = src + (size_t)m * H;
    unsigned short* d = dst + (size_t)m * KS;
    for (int k = threadIdx.x; k < H; k += 256){
        float v = s[k];
        unsigned short hi = f2bf(v);
        d[k]     = hi;
        d[H + k] = f2bf(v - bf2f(hi));
    }
}

__global__ __launch_bounds__(256) void split_w(
    const float* __restrict__ wq, const float* __restrict__ wk,
    const float* __restrict__ wv, const float* __restrict__ wo,
    unsigned short* __restrict__ Wqkv, unsigned short* __restrict__ Wo_)
{
    const int n = blockIdx.x;      // 0..767
    const int w = blockIdx.y;      // 0..3
    const float* src = (w==0)?wq:(w==1)?wk:(w==2)?wv:wo;
    unsigned short* dst = (w<3) ? &Wqkv[(size_t)(w*768 + n)*KS] : &Wo_[(size_t)n*KS];
    const float* s = src + (size_t)n * H;
    for (int k = threadIdx.x; k < H; k += 256){
        float v = s[k];
        unsigned short hi = f2bf(v);
        dst[k]     = hi;
        dst[H + k] = f2bf(v - bf2f(hi));
    }
}

// ---------------------------------------------------------------------------
// Split-bf16 GEMM: Y[m][n] = sum_k X[m][k]*W[n][k] + bias  (fp32-accurate)
// A = [Xhi|Xlo] (phase seq hi,hi,lo -> ka = k'<768 ? k' : k'-768)
// B = [Whi|Wlo] (phase seq hi,lo,hi -> kb = k'<1536 ? k' : k'-1536)
// 128x128 tile, 4 waves 2x2, BK=32, global_load_lds + XOR chunk swizzle.
// MODE 0: fp32 store + bias.  MODE 1: QKV scatter (Q scaled 1/8, V transposed).
// ---------------------------------------------------------------------------
template<int MODE>
__global__ __launch_bounds__(256) void gemm_split(
    const unsigned short* __restrict__ A, const unsigned short* __restrict__ Bm,
    const float* __restrict__ b0, const float* __restrict__ b1,
    const float* __restrict__ b2,
    float* __restrict__ out,
    unsigned short* __restrict__ Qh, unsigned short* __restrict__ Ql,
    unsigned short* __restrict__ Kh, unsigned short* __restrict__ Kl,
    unsigned short* __restrict__ Vh, unsigned short* __restrict__ Vl)
{
    __shared__ unsigned short As[128*32];
    __shared__ unsigned short Bs[128*32];
    const int tid = threadIdx.x, lane = tid & 63, wave = tid >> 6;
    const int m0 = blockIdx.x*128, n0 = blockIdx.y*128;
    const int wr = wave >> 1, wc = wave & 1;
    const int frow = lane & 15, foct = lane >> 4;
    const int arow = lane >> 2;                        // 16 rows per GLL (64B rows)
    const int achk = ((lane & 3) ^ (arow & 3)) * 8;    // pre-swizzled source chunk
    const int fswz = (foct ^ (frow & 3)) * 8;          // swizzled read chunk

    f32x4 acc[4][4] = {};

    for (int kp = 0; kp < KP; kp += 32){
        const int ka = (kp < 768)  ? kp : kp - 768;
        const int kb = (kp < 1536) ? kp : kp - 1536;
        __syncthreads();
        #pragma unroll
        for (int i = 0; i < 2; ++i){
            const int r0 = (wave*2 + i)*16;
            const int row = r0 + arow;
            GLL16(A  + (size_t)(m0+row)*KS + ka + achk, &As[r0*32]);
            GLL16(Bm + (size_t)(n0+row)*KS + kb + achk, &Bs[r0*32]);
        }
        __syncthreads();
        bf16x8 af[4], bfv[4];
        #pragma unroll
        for (int i = 0; i < 4; ++i)
            af[i]  = *(const bf16x8*)&As[(wr*64 + 16*i + frow)*32 + fswz];
        #pragma unroll
        for (int j = 0; j < 4; ++j)
            bfv[j] = *(const bf16x8*)&Bs[(wc*64 + 16*j + frow)*32 + fswz];
        #pragma unroll
        for (int i = 0; i < 4; ++i)
            #pragma unroll
            for (int j = 0; j < 4; ++j)
                acc[i][j] = MFMA(af[i], bfv[j], acc[i][j]);
    }

    if (MODE == 0){
        #pragma unroll
        for (int i = 0; i < 4; ++i){
            const int m = m0 + wr*64 + 16*i + 4*foct;
            #pragma unroll
            for (int j = 0; j < 4; ++j){
                const int n = n0 + wc*64 + 16*j + frow;
                const float bb = b0[n];
                #pragma unroll
                for (int r = 0; r < 4; ++r)
                    out[(size_t)(m + r)*H + n] = acc[i][j][r] + bb;
            }
        }
    } else {
        const int sect = n0 / 768;                     // 0=Q 1=K 2=V (block-uniform)
        const float* bias = (sect==0) ? b0 : (sect==1) ? b1 : b2;
        const float qs = (sect==0) ? 0.125f : 1.0f;    // fold 1/sqrt(HD) into Q
        unsigned short* Ph = (sect==0) ? Qh : Kh;
        unsigned short* Pl = (sect==0) ? Ql : Kl;
        #pragma unroll
        for (int i = 0; i < 4; ++i){
            const int m  = m0 + wr*64 + 16*i + 4*foct; // rows m..m+3
            const int bb = m >> 11, ss = m & (S_-1);
            #pragma unroll
            for (int j = 0; j < 4; ++j){
                const int nn = (n0 - sect*768) + wc*64 + 16*j + frow;
                const float bv_ = bias[nn];
                const int hh = nn >> 6, dd = nn & 63;
                unsigned short hi[4], lo[4];
                #pragma unroll
                for (int r = 0; r < 4; ++r){
                    float v = (acc[i][j][r] + bv_) * qs;
                    hi[r] = f2bf(v);
                    lo[r] = f2bf(v - bf2f(hi[r]));
                }
                if (sect < 2){                         // [b][h][s][d]
                    const size_t base = ((size_t)(bb*NH + hh)*S_)*HD + dd;
                    #pragma unroll
                    for (int r = 0; r < 4; ++r){
                        Ph[base + (size_t)(ss + r)*HD] = hi[r];
                        Pl[base + (size_t)(ss + r)*HD] = lo[r];
                    }
                } else {                               // V transposed [b][h][d][s]
                    const size_t a = ((size_t)(bb*NH + hh)*HD + dd)*S_ + ss;
                    ushort4 ph; ph.x=hi[0]; ph.y=hi[1]; ph.z=hi[2]; ph.w=hi[3];
                    ushort4 pl; pl.x=lo[0]; pl.y=lo[1]; pl.z=lo[2]; pl.w=lo[3];
                    *(ushort4*)&Vh[a] = ph;
                    *(ushort4*)&Vl[a] = pl;
                }
            }
        }
    }
}

// ---------------------------------------------------------------------------
// Flash attention, MFMA. 4 waves; wave w owns q-rows [16w,16w+16) of a 64-row
// tile. K/V 64-key tiles staged via global_load_lds with row&7 XOR swizzle.
// QK^T = 3 mfma (split Q,K); PV = 2 mfma (bf16 P, split V). P wave-local LDS.
// ---------------------------------------------------------------------------
__global__ __launch_bounds__(256) void attn_mfma(
    const unsigned short* __restrict__ Qh, const unsigned short* __restrict__ Ql,
    const unsigned short* __restrict__ Kh, const unsigned short* __restrict__ Kl,
    const unsigned short* __restrict__ Vh, const unsigned short* __restrict__ Vl,
    const int* __restrict__ mask, unsigned short* __restrict__ Cs)
{
    __shared__ unsigned short Ksh[64*64], Ksl[64*64], Vsh[64*64], Vsl[64*64], Ps[64*64];
    const int tid = threadIdx.x, lane = tid & 63, wave = tid >> 6;
    const int q0 = blockIdx.x*64, h = blockIdx.y, b = blockIdx.z;
    const int frow = lane & 15, foct = lane >> 4;
    const size_t base  = (size_t)(b*NH + h)*S_;   // K rows [s][d]
    const size_t vbase = (size_t)(b*NH + h)*HD;   // V rows [d][s]

    bf16x8 aqh[2], aql[2];
    {
        const size_t qr = (base + q0 + wave*16 + frow)*HD;
        #pragma unroll
        for (int ks = 0; ks < 2; ++ks){
            aqh[ks] = *(const bf16x8*)&Qh[qr + ks*32 + foct*8];
            aql[ks] = *(const bf16x8*)&Ql[qr + ks*32 + foct*8];
        }
    }

    float mrow[4], lrow[4];
    f32x4 o[4] = {};
    #pragma unroll
    for (int r = 0; r < 4; ++r){ mrow[r] = -1e30f; lrow[r] = 0.f; }

    const int srow = lane >> 3;                  // 8 rows per GLL (128B rows)
    const int schk = ((lane & 7) ^ srow) * 8;    // pre-swizzled source chunk
    const int fsw7 = frow & 7;

    for (int t = 0; t < S_/64; ++t){
        __syncthreads();
        #pragma unroll
        for (int i = 0; i < 2; ++i){
            const int r0 = (wave*2 + i)*8;
            const int row = r0 + srow;
            const size_t ko = (base + t*64 + row)*HD + schk;
            GLL16(Kh + ko, &Ksh[r0*64]);
            GLL16(Kl + ko, &Ksl[r0*64]);
            const size_t vo = (vbase + row)*S_ + t*64 + schk;
            GLL16(Vh + vo, &Vsh[r0*64]);
            GLL16(Vl + vo, &Vsl[r0*64]);
        }
        __syncthreads();

        f32x4 sf[4] = {};
        #pragma unroll
        for (int ks = 0; ks < 2; ++ks){
            #pragma unroll
            for (int j = 0; j < 4; ++j){
                const int ad = (16*j + frow)*64 + ((ks*4 + foct) ^ fsw7)*8;
                const bf16x8 kh = *(const bf16x8*)&Ksh[ad];
                const bf16x8 kl = *(const bf16x8*)&Ksl[ad];
                sf[j] = MFMA(aqh[ks], kh, sf[j]);
                sf[j] = MFMA(aqh[ks], kl, sf[j]);
                sf[j] = MFMA(aql[ks], kh, sf[j]);
            }
        }

        #pragma unroll
        for (int j = 0; j < 4; ++j){
            if (mask[b*S_ + t*64 + 16*j + frow] == 0){
                #pragma unroll
                for (int r = 0; r < 4; ++r) sf[j][r] = -1e9f;
            }
        }

        // online softmax (rows 4*foct+r, reduce across the 16 frow lanes)
        #pragma unroll
        for (int r = 0; r < 4; ++r){
            float x = fmaxf(fmaxf(sf[0][r], sf[1][r]), fmaxf(sf[2][r], sf[3][r]));
            x = fmaxf(x, __shfl_xor(x, 1));
            x = fmaxf(x, __shfl_xor(x, 2));
            x = fmaxf(x, __shfl_xor(x, 4));
            x = fmaxf(x, __shfl_xor(x, 8));
            const float mnew = fmaxf(mrow[r], x);
            const float sc = __expf(mrow[r] - mnew);
            mrow[r] = mnew;
            float p[4], ps = 0.f;
            #pragma unroll
            for (int j = 0; j < 4; ++j){ p[j] = __expf(sf[j][r] - mnew); ps += p[j]; }
            ps += __shfl_xor(ps, 1);
            ps += __shfl_xor(ps, 2);
            ps += __shfl_xor(ps, 4);
            ps += __shfl_xor(ps, 8);
            lrow[r] = lrow[r]*sc + ps;
            #pragma unroll
            for (int j = 0; j < 4; ++j) o[j][r] *= sc;
            const int prow = wave*16 + 4*foct + r;
            const int psw = (4*foct + r) & 7;
            #pragma unroll
            for (int j = 0; j < 4; ++j){
                const int col = 16*j + frow;
                Ps[prow*64 + ((col >> 3) ^ psw)*8 + (col & 7)] = f2bf(p[j]);
            }
        }

        // PV (P rows are wave-local: no barrier needed)
        #pragma unroll
        for (int ks = 0; ks < 2; ++ks){
            const bf16x8 pa = *(const bf16x8*)&Ps[(wave*16 + frow)*64 + ((ks*4 + foct) ^ fsw7)*8];
            #pragma unroll
            for (int j = 0; j < 4; ++j){
                const int ad = (16*j + frow)*64 + ((ks*4 + foct) ^ fsw7)*8;
                o[j] = MFMA(pa, *(const bf16x8*)&Vsh[ad], o[j]);
                o[j] = MFMA(pa, *(const bf16x8*)&Vsl[ad], o[j]);
            }
        }
    }

    // epilogue: normalize, write ctx directly in split form [m][hi|lo]
    #pragma unroll
    for (int r = 0; r < 4; ++r){
        const float inv = 1.0f / lrow[r];
        const int sg = q0 + wave*16 + 4*foct + r;
        const size_t g = (size_t)(b*S_ + sg)*KS;
        #pragma unroll
        for (int j = 0; j < 4; ++j){
            const int col = h*HD + 16*j + frow;
            const float val = o[j][r]*inv;
            const unsigned short hi = f2bf(val);
            Cs[g + col]       = hi;
            Cs[g + 768 + col] = f2bf(val - bf2f(hi));
        }
    }
}

extern "C" void kernel_launch(void* const* d_in, const int* in_sizes, int n_in,
                              void* d_out, int out_size, void* d_ws, size_t ws_size,
                              hipStream_t stream) {
    const float* hs = (const float*)d_in[0];
    const int*  msk = (const int*)  d_in[1];
    const float* wq = (const float*)d_in[2];
    const float* bq = (const float*)d_in[3];
    const float* wk = (const float*)d_in[4];
    const float* bk = (const float*)d_in[5];
    const float* wv = (const float*)d_in[6];
    const float* bv = (const float*)d_in[7];
    const float* wo = (const float*)d_in[8];
    const float* bo = (const float*)d_in[9];
    float* out = (float*)d_out;

    const size_t XS_E   = (size_t)MTOT*KS;        // 6.29M shorts
    const size_t WQKV_E = (size_t)2304*KS;
    const size_t WO_E   = (size_t)768*KS;
    const size_t QKV_E  = (size_t)B_*NH*S_*HD;    // 3.15M shorts

    unsigned short* p = (unsigned short*)d_ws;
    unsigned short* Xs   = p; p += XS_E;          // later reused as Cs
    unsigned short* Wqkv = p; p += WQKV_E;
    unsigned short* Wo_  = p; p += WO_E;
    unsigned short* Qh = p; p += QKV_E;
    unsigned short* Ql = p; p += QKV_E;
    unsigned short* Kh = p; p += QKV_E;
    unsigned short* Kl = p; p += QKV_E;
    unsigned short* Vh = p; p += QKV_E;
    unsigned short* Vl = p; p += QKV_E;
    unsigned short* Cs = Xs;

    split_x<<<dim3(MTOT), 256, 0, stream>>>(hs, Xs);
    split_w<<<dim3(768, 4), 256, 0, stream>>>(wq, wk, wv, wo, Wqkv, Wo_);
    gemm_split<1><<<dim3(MTOT/128, KP/128), 256, 0, stream>>>(
        Xs, Wqkv, bq, bk, bv, nullptr, Qh, Ql, Kh, Kl, Vh, Vl);
    attn_mfma<<<dim3(S_/64, NH, B_), 256, 0, stream>>>(
        Qh, Ql, Kh, Kl, Vh, Vl, msk, Cs);
    gemm_split<0><<<dim3(MTOT/128, H/128), 256, 0, stream>>>(
        Cs, Wo_, bo, nullptr, nullptr, out,
        nullptr, nullptr, nullptr, nullptr, nullptr, nullptr);
}